// Round 13
// baseline (309.542 us; speedup 1.0000x reference)
//
#include <hip/hip_runtime.h>
#include <hip/hip_bf16.h>
#include <math.h>

#define N_USER 100000
#define N_ITEM 50000
#define NNODE  150000   // N_USER + N_ITEM
#define DIM    64
#define NEDGE  2000000
#define BSZ    8192
#define NTGT   (3*BSZ)
#define CB     586      // ceil(NNODE/256) coarse buckets
#define NB     512      // edge chunks
#define CH     ((NEDGE + NB - 1)/NB)   // 3907
#define LBLK   2048
#define CAP    5120     // k_build per-bucket LDS capacity
#define BSLACK 772      // per-bucket ec slack for row padding (3*256 + align)

typedef float v2f __attribute__((ext_vector_type(2)));
typedef unsigned v4u __attribute__((ext_vector_type(4)));

__device__ __forceinline__ float logsigf(float x){
    return fminf(x, 0.f) - log1pf(expf(-fabsf(x)));
}
__device__ __forceinline__ float softplusf(float x){
    return fmaxf(x, 0.f) + log1pf(expf(-fabsf(x)));
}
__device__ __forceinline__ v2f fp8x2_to_f32(unsigned short u){
    return __builtin_amdgcn_cvt_pk_f32_fp8((int)u, false);
}
__device__ __forceinline__ unsigned short f32_to_fp8x2(float a, float b){
    return (unsigned short)__builtin_amdgcn_cvt_pk_fp8_f32(a, b, 0, false);
}
__device__ __forceinline__ unsigned rfl(unsigned v){
    return (unsigned)__builtin_amdgcn_readfirstlane((int)v);
}
__device__ __forceinline__ v4u nt4(const unsigned* p){
    return __builtin_nontemporal_load((const v4u*)p);
}
__device__ __forceinline__ unsigned umin2(unsigned a, unsigned b){ return a<b ? a : b; }

// exclusive scan of arr[CB] with 512 threads (each owns 2 slots)
__device__ __forceinline__ void scanCB512(unsigned* arr, unsigned* tmp){
    int t = threadIdx.x;
    int base = 2*t;
    unsigned a0=0,a1=0;
    if(base   < CB) a0 = arr[base];
    if(base+1 < CB) a1 = arr[base+1];
    unsigned s = a0+a1;
    tmp[t]=s; __syncthreads();
    for(int off=1; off<512; off<<=1){
        unsigned v = (t>=off)? tmp[t-off] : 0u;
        __syncthreads();
        tmp[t] += v;
        __syncthreads();
    }
    unsigned excl = tmp[t]-s;
    if(base   < CB) arr[base]   = excl;
    if(base+1 < CB) arr[base+1] = excl+a0;
    __syncthreads();
}

// ==== coarse histograms, both sides, LDS-only ([chunk][bin]) + mask ======
__global__ __launch_bounds__(512) void k_hist(const int* __restrict__ src, const int* __restrict__ dst,
                       unsigned* __restrict__ histD, unsigned* __restrict__ histS,
                       const unsigned char* __restrict__ mask8, unsigned* __restrict__ mflag){
    if(blockIdx.x == NB){
        __shared__ int any;
        if(threadIdx.x==0) any=0;
        __syncthreads();
        for(int i=threadIdx.x;i<BSZ;i+=512){ if((i&3) && mask8[i]) any=1; }
        __syncthreads();
        if(threadIdx.x==0) *mflag = (any!=0) ? 1u : 0u;
        return;
    }
    __shared__ unsigned hD[CB], hS[CB];
    for(int i=threadIdx.x;i<CB;i+=512){ hD[i]=0; hS[i]=0; }
    __syncthreads();
    int lo = blockIdx.x*CH, hi = min(lo+CH, NEDGE);
    for(int e=lo+threadIdx.x; e<hi; e+=512){
        atomicAdd(&hS[src[e]>>8],1u);
        atomicAdd(&hD[dst[e]>>8],1u);
    }
    __syncthreads();
    for(int i=threadIdx.x;i<CB;i+=512){          // contiguous full-line writes
        histD[(size_t)blockIdx.x*CB + i]=hD[i];
        histS[(size_t)blockIdx.x*CB + i]=hS[i];
    }
}

// scan along chunks for each bucket; strided access into L2-resident array
__global__ __launch_bounds__(512) void k_colscan(unsigned* __restrict__ histD, unsigned* __restrict__ histS,
                          unsigned* __restrict__ ctD, unsigned* __restrict__ ctS){
    unsigned* hist = blockIdx.y ? histS : histD;
    unsigned* ct   = blockIdx.y ? ctS   : ctD;
    int b = blockIdx.x;
    __shared__ unsigned sh[512];
    unsigned v = hist[(size_t)threadIdx.x*CB + b];
    sh[threadIdx.x] = v;
    __syncthreads();
    for(int off=1; off<512; off<<=1){
        unsigned t = (threadIdx.x>=off)? sh[threadIdx.x-off] : 0u;
        __syncthreads();
        sh[threadIdx.x] += t;
        __syncthreads();
    }
    hist[(size_t)threadIdx.x*CB + b] = sh[threadIdx.x] - v;
    if(threadIdx.x==511) ct[b] = sh[511];
}

__global__ __launch_bounds__(1024) void k_bstart(const unsigned* __restrict__ ctD, const unsigned* __restrict__ ctS,
                         unsigned* __restrict__ bsD, unsigned* __restrict__ bsS){
    __shared__ unsigned sh[1024];
    unsigned v = (threadIdx.x<CB)? ctD[threadIdx.x] : 0u;
    sh[threadIdx.x]=v; __syncthreads();
    for(int off=1; off<1024; off<<=1){ unsigned t=(threadIdx.x>=off)?sh[threadIdx.x-off]:0u; __syncthreads(); sh[threadIdx.x]+=t; __syncthreads(); }
    if(threadIdx.x<CB) bsD[threadIdx.x]=sh[threadIdx.x]-v;
    if(threadIdx.x==CB-1) bsD[CB]=sh[threadIdx.x];
    __syncthreads();
    unsigned v2 = (threadIdx.x<CB)? ctS[threadIdx.x] : 0u;
    sh[threadIdx.x]=v2; __syncthreads();
    for(int off=1; off<1024; off<<=1){ unsigned t=(threadIdx.x>=off)?sh[threadIdx.x-off]:0u; __syncthreads(); sh[threadIdx.x]+=t; __syncthreads(); }
    if(threadIdx.x<CB) bsS[threadIdx.x]=sh[threadIdx.x]-v2;
    if(threadIdx.x==CB-1) bsS[CB]=sh[threadIdx.x];
}

// ==== scatter with LDS reorder, 512 threads ==============================
__global__ __launch_bounds__(512) void k_scatter(const int* __restrict__ src, const int* __restrict__ dst,
                          const unsigned* __restrict__ histD, const unsigned* __restrict__ histS,
                          const unsigned* __restrict__ bsD, const unsigned* __restrict__ bsS,
                          unsigned* __restrict__ part, unsigned char* __restrict__ spart){
    __shared__ unsigned curD[CB], curS[CB];
    __shared__ unsigned lhD[CB], lhS[CB];
    __shared__ unsigned startD[CB], startS[CB];
    __shared__ unsigned tmp[512];
    __shared__ unsigned partl[CH];
    __shared__ unsigned short keyD[CH];
    __shared__ unsigned short keyS[CH];
    __shared__ unsigned char sl[CH];
    for(int i=threadIdx.x;i<CB;i+=512){
        curD[i]=bsD[i]+histD[(size_t)blockIdx.x*CB+i];
        curS[i]=bsS[i]+histS[(size_t)blockIdx.x*CB+i];
        lhD[i]=0; lhS[i]=0;
    }
    __syncthreads();
    int lo=blockIdx.x*CH, hi=min(lo+CH,NEDGE);
    int n = hi-lo;
    for(int e=lo+threadIdx.x;e<hi;e+=512){
        atomicAdd(&lhD[dst[e]>>8],1u);
        atomicAdd(&lhS[src[e]>>8],1u);
    }
    __syncthreads();
    scanCB512(lhD, tmp);
    scanCB512(lhS, tmp);
    for(int i=threadIdx.x;i<CB;i+=512){ startD[i]=lhD[i]; startS[i]=lhS[i]; }
    __syncthreads();
    for(int e=lo+threadIdx.x;e<hi;e+=512){
        int s=src[e], d=dst[e];
        unsigned bd=(unsigned)(d>>8);
        unsigned slot=atomicAdd(&lhD[bd],1u);
        partl[slot]=((unsigned)(d&255)<<18)|(unsigned)s;
        keyD[slot]=(unsigned short)bd;
        unsigned bs=(unsigned)(s>>8);
        unsigned sslot=atomicAdd(&lhS[bs],1u);
        sl[sslot]=(unsigned char)(s&255);
        keyS[sslot]=(unsigned short)bs;
    }
    __syncthreads();
    for(int k=threadIdx.x;k<n;k+=512){
        unsigned b=keyD[k];
        part[curD[b] + (unsigned)k - startD[b]] = partl[k];
    }
    for(int k=threadIdx.x;k<n;k+=512){
        unsigned b=keyS[k];
        spart[curS[b] + (unsigned)k - startS[b]] = sl[k];
    }
}

// ==== fused per-bucket build: degO + csr + fp8 prep ======================
// Phase 1: out-degree from spart bucket -> rsqO in LDS, sqd to global.
// Phase 2: csr (padded rows, guard edges, ec byte offsets, srow/rsqI8).
// Phase 3: fp8 prep for this bucket's 256 nodes with LDS rsqO scale.
__global__ __launch_bounds__(256) void k_build(const unsigned char* __restrict__ spart, const unsigned* __restrict__ bsS,
                      const unsigned* __restrict__ part, const unsigned* __restrict__ bsD,
                      const float4* __restrict__ ei, const float4* __restrict__ ep,
                      unsigned* __restrict__ rs, unsigned* __restrict__ degI,
                      unsigned* __restrict__ ec, float* __restrict__ srow, float* __restrict__ rsqI8,
                      float* __restrict__ sqd,
                      unsigned* __restrict__ hE32, unsigned* __restrict__ h1g, unsigned* __restrict__ h2g){
    if(blockIdx.x == CB){          // guard rows for hE/h1/h2 (fp8 zeros)
        int t = threadIdx.x;
        if(t < 32) hE32[t] = 0u;
        else if(t < 64) h1g[t-32] = 0u;
        else if(t < 96) h2g[t-64] = 0u;
        return;
    }
    __shared__ unsigned cnt[256], cur[256], sh[256];
    __shared__ unsigned stR[256], exR[256];
    __shared__ float rsqOl[256];
    __shared__ unsigned partl[CAP];
    int tid = threadIdx.x;
    int node=(blockIdx.x<<8)+tid;
    // --- phase 1: out-degree ---
    cnt[tid]=0; __syncthreads();
    {
        unsigned slo=bsS[blockIdx.x], shi=bsS[blockIdx.x+1];
        for(unsigned e=slo+tid;e<shi;e+=256) atomicAdd(&cnt[spart[e]],1u);
    }
    __syncthreads();
    {
        float dv = fmaxf((float)cnt[tid],1.f);
        rsqOl[tid]=rsqrtf(dv);
        if(node<NNODE) sqd[node]=sqrtf(dv)*0.125f;   // (1/rsqO)/8 for scoreloss
    }
    __syncthreads();
    // --- phase 2: csr ---
    cnt[tid]=0; __syncthreads();
    unsigned lo=bsD[blockIdx.x], hi=bsD[blockIdx.x+1];
    unsigned n = hi-lo;
    for(unsigned e=lo+tid;e<hi;e+=256) atomicAdd(&cnt[part[e]>>18],1u);
    __syncthreads();
    unsigned c=cnt[tid];
    unsigned r4=(c+3u)&~3u;
    sh[tid]=c; __syncthreads();
    for(int o=1;o<256;o<<=1){ unsigned t2=(tid>=o)?sh[tid-o]:0u; __syncthreads(); sh[tid]+=t2; __syncthreads(); }
    unsigned ex = sh[tid]-c;
    __syncthreads();
    sh[tid]=r4; __syncthreads();
    for(int o=1;o<256;o<<=1){ unsigned t2=(tid>=o)?sh[tid-o]:0u; __syncthreads(); sh[tid]+=t2; __syncthreads(); }
    unsigned ex_r = sh[tid]-r4;
    stR[tid]=ex; exR[tid]=ex_r;
    cur[tid]=(n<=CAP)? ex : ex_r;
    unsigned lo_ec = ((lo+3u)&~3u) + (unsigned)BSLACK*blockIdx.x;
    if(node<NNODE){
        degI[node]=r4; rs[node]=lo_ec+ex_r;
        float rI = rsqrtf(fmaxf((float)c,1.f));   // REAL in-degree for norm
        srow[node]  = rI*rsqOl[tid];   // 8-factors cancel
        rsqI8[node] = rI*0.125f;       // layer-3 epilogue scale
    }
    for(unsigned j=c;j<r4;++j) ec[lo_ec+ex_r+j]=0u;   // guard-fill pads
    __syncthreads();
    if(n <= CAP){
        for(unsigned e=lo+tid;e<hi;e+=256){
            unsigned p=part[e];
            unsigned slot=atomicAdd(&cur[p>>18],1u);
            partl[slot]=p;
        }
        __syncthreads();
        for(unsigned k=tid;k<n;k+=256){
            unsigned p=partl[k];
            unsigned fb=p>>18;
            ec[lo_ec + exR[fb] + (k - stR[fb])] = ((p&0x3FFFFu)+1u)<<7;
        }
    } else {
        for(unsigned e=lo+tid;e<hi;e+=256){
            unsigned p=part[e];
            unsigned pos=lo_ec+atomicAdd(&cur[p>>18],1u);
            ec[pos] = ((p&0x3FFFFu)+1u)<<7;
        }
    }
    // --- phase 3: fp8 prep (stored = 8*rsqO*h, e4m3 normal range) ---
    for(int j=0;j<32;++j){
        int idx = j*256 + tid;
        int nl = idx>>5, cc = idx&31;
        int nd = (blockIdx.x<<8)+nl;
        if(nd >= NNODE) break;
        float sc = 8.f*rsqOl[nl];
        float4 v;
        if(cc<16) v = ei[(size_t)nd*16 + cc];
        else      v = ep[(size_t)nd*16 + (cc-16)];
        int d = __builtin_amdgcn_cvt_pk_fp8_f32(v.x*sc, v.y*sc, 0, false);
        d = __builtin_amdgcn_cvt_pk_fp8_f32(v.z*sc, v.w*sc, d, true);
        hE32[32 + (size_t)nd*32 + cc] = (unsigned)d;   // +32 dwords skips guard row
    }
}

// ==== SpMM: 4 rows/wave joint loop + rotating e-prefetch =================
__device__ __forceinline__ void drain4(const char* __restrict__ hb,
                                       const unsigned* __restrict__ ec,
                                       unsigned s, unsigned c, unsigned &i, unsigned lane2,
                                       v2f &acc){
    for(; i+4<=c; i+=4){
        v4u e = nt4(&ec[s+i]);
        unsigned short u0=*(const unsigned short*)(hb+e.x+lane2);
        unsigned short u1=*(const unsigned short*)(hb+e.y+lane2);
        unsigned short u2=*(const unsigned short*)(hb+e.z+lane2);
        unsigned short u3=*(const unsigned short*)(hb+e.w+lane2);
        acc += fp8x2_to_f32(u0); acc += fp8x2_to_f32(u1);
        acc += fp8x2_to_f32(u2); acc += fp8x2_to_f32(u3);
    }
}

__global__ __launch_bounds__(256) void k_spmm_c(const unsigned short* __restrict__ hinb, unsigned short* __restrict__ houtb,
                                                const unsigned* __restrict__ rs, const unsigned* __restrict__ degI,
                                                const unsigned* __restrict__ ec, const float* __restrict__ srow){
    int wv = (blockIdx.x*256 + threadIdx.x) >> 6;
    int lane = threadIdx.x & 63;
    int r = 4*wv;                         // NNODE % 4 == 0, natural order
    if(r >= NNODE) return;
    unsigned s0=rfl(rs[r  ]), c0=rfl(degI[r  ]);
    unsigned s1=rfl(rs[r+1]), c1=rfl(degI[r+1]);
    unsigned s2=rfl(rs[r+2]), c2=rfl(degI[r+2]);
    unsigned s3=rfl(rs[r+3]), c3=rfl(degI[r+3]);
    const char* hb = (const char*)hinb;
    unsigned lane2 = ((unsigned)lane)*2u;
    v2f a0={0.f,0.f}, a1={0.f,0.f}, a2={0.f,0.f}, a3={0.f,0.f};
    unsigned m = umin2(umin2(c0,c1), umin2(c2,c3));   // multiple of 4
    v4u eA, eB, eC, eD;
    if(m){
        eA=nt4(&ec[s0]); eB=nt4(&ec[s1]); eC=nt4(&ec[s2]); eD=nt4(&ec[s3]);
    }
    for(unsigned i=0; i<m; i+=4){
        unsigned ip = (i+4<m) ? i+4 : 0u;            // clamped: last iter reloads offset 0
        v4u fA=nt4(&ec[s0+ip]), fB=nt4(&ec[s1+ip]), fC=nt4(&ec[s2+ip]), fD=nt4(&ec[s3+ip]);
        unsigned short u00=*(const unsigned short*)(hb+eA.x+lane2);
        unsigned short u01=*(const unsigned short*)(hb+eA.y+lane2);
        unsigned short u02=*(const unsigned short*)(hb+eA.z+lane2);
        unsigned short u03=*(const unsigned short*)(hb+eA.w+lane2);
        unsigned short u10=*(const unsigned short*)(hb+eB.x+lane2);
        unsigned short u11=*(const unsigned short*)(hb+eB.y+lane2);
        unsigned short u12=*(const unsigned short*)(hb+eB.z+lane2);
        unsigned short u13=*(const unsigned short*)(hb+eB.w+lane2);
        unsigned short u20=*(const unsigned short*)(hb+eC.x+lane2);
        unsigned short u21=*(const unsigned short*)(hb+eC.y+lane2);
        unsigned short u22=*(const unsigned short*)(hb+eC.z+lane2);
        unsigned short u23=*(const unsigned short*)(hb+eC.w+lane2);
        unsigned short u30=*(const unsigned short*)(hb+eD.x+lane2);
        unsigned short u31=*(const unsigned short*)(hb+eD.y+lane2);
        unsigned short u32v=*(const unsigned short*)(hb+eD.z+lane2);
        unsigned short u33=*(const unsigned short*)(hb+eD.w+lane2);
        a0 += fp8x2_to_f32(u00); a0 += fp8x2_to_f32(u01); a0 += fp8x2_to_f32(u02); a0 += fp8x2_to_f32(u03);
        a1 += fp8x2_to_f32(u10); a1 += fp8x2_to_f32(u11); a1 += fp8x2_to_f32(u12); a1 += fp8x2_to_f32(u13);
        a2 += fp8x2_to_f32(u20); a2 += fp8x2_to_f32(u21); a2 += fp8x2_to_f32(u22); a2 += fp8x2_to_f32(u23);
        a3 += fp8x2_to_f32(u30); a3 += fp8x2_to_f32(u31); a3 += fp8x2_to_f32(u32v); a3 += fp8x2_to_f32(u33);
        eA=fA; eB=fB; eC=fC; eD=fD;
    }
    unsigned i0=m,i1=m,i2=m,i3=m;
    drain4(hb, ec, s0, c0, i0, lane2, a0);
    drain4(hb, ec, s1, c1, i1, lane2, a1);
    drain4(hb, ec, s2, c2, i2, lane2, a2);
    drain4(hb, ec, s3, c3, i3, lane2, a3);
    float sc0=srow[r], sc1=srow[r+1], sc2=srow[r+2], sc3=srow[r+3];
    houtb[(size_t)(r+1)*64+lane] = f32_to_fp8x2(sc0*a0.x, sc0*a0.y);
    houtb[(size_t)(r+2)*64+lane] = f32_to_fp8x2(sc1*a1.x, sc1*a1.y);
    houtb[(size_t)(r+3)*64+lane] = f32_to_fp8x2(sc2*a2.x, sc2*a2.y);
    houtb[(size_t)(r+4)*64+lane] = f32_to_fp8x2(sc3*a3.x, sc3*a3.y);
}

// ==== fused layer-3 gather + score + loss: one wave per sample ===========
__global__ __launch_bounds__(256) void k_scoreloss(const float2* __restrict__ ei, const float2* __restrict__ ep,
                        const unsigned short* __restrict__ h1C, const unsigned short* __restrict__ h2C,
                        const unsigned* __restrict__ rs, const unsigned* __restrict__ degI,
                        const unsigned* __restrict__ ec, const float* __restrict__ rsqI8,
                        const float* __restrict__ q, const float* __restrict__ bq,
                        const int* __restrict__ user, const int* __restrict__ item_p, const int* __restrict__ item_n,
                        const void* __restrict__ mask, const unsigned* __restrict__ mflag,
                        const float* __restrict__ sqd,
                        float4* __restrict__ partial){
    int t = blockIdx.x*256 + threadIdx.x;
    int b = t >> 6, l = t & 63;
    int wv = threadIdx.x >> 6;
    __shared__ float4 wsum[4];
    int nu = __builtin_amdgcn_readfirstlane(user[b]);
    int np = __builtin_amdgcn_readfirstlane(item_p[b]) + N_USER;
    int nn = __builtin_amdgcn_readfirstlane(item_n[b]) + N_USER;

    // --- in-wave layer-3 gather over h2C for the 3 target rows ---
    unsigned s0 = rfl(rs[nu]), c0 = rfl(degI[nu]);
    unsigned s1 = rfl(rs[np]), c1 = rfl(degI[np]);
    unsigned s2 = rfl(rs[nn]), c2 = rfl(degI[nn]);
    const char* hb = (const char*)h2C;
    unsigned lane2 = ((unsigned)l)*2u;
    v2f g0={0.f,0.f}, g1={0.f,0.f}, g2={0.f,0.f};
    unsigned m = umin2(umin2(c0,c1), c2);
    for(unsigned i=0; i<m; i+=4){
        v4u eA=nt4(&ec[s0+i]), eB=nt4(&ec[s1+i]), eC=nt4(&ec[s2+i]);
        unsigned short u0=*(const unsigned short*)(hb+eA.x+lane2);
        unsigned short u1=*(const unsigned short*)(hb+eA.y+lane2);
        unsigned short u2=*(const unsigned short*)(hb+eA.z+lane2);
        unsigned short u3=*(const unsigned short*)(hb+eA.w+lane2);
        unsigned short u4=*(const unsigned short*)(hb+eB.x+lane2);
        unsigned short u5=*(const unsigned short*)(hb+eB.y+lane2);
        unsigned short u6=*(const unsigned short*)(hb+eB.z+lane2);
        unsigned short u7=*(const unsigned short*)(hb+eB.w+lane2);
        unsigned short u8=*(const unsigned short*)(hb+eC.x+lane2);
        unsigned short u9=*(const unsigned short*)(hb+eC.y+lane2);
        unsigned short ua=*(const unsigned short*)(hb+eC.z+lane2);
        unsigned short ub=*(const unsigned short*)(hb+eC.w+lane2);
        g0 += fp8x2_to_f32(u0); g0 += fp8x2_to_f32(u1); g0 += fp8x2_to_f32(u2); g0 += fp8x2_to_f32(u3);
        g1 += fp8x2_to_f32(u4); g1 += fp8x2_to_f32(u5); g1 += fp8x2_to_f32(u6); g1 += fp8x2_to_f32(u7);
        g2 += fp8x2_to_f32(u8); g2 += fp8x2_to_f32(u9); g2 += fp8x2_to_f32(ua); g2 += fp8x2_to_f32(ub);
    }
    unsigned i0=m, i1=m, i2=m;
    drain4(hb, ec, s0, c0, i0, lane2, g0);
    drain4(hb, ec, s1, c1, i1, lane2, g1);
    drain4(hb, ec, s2, c2, i2, lane2, g2);
    float t0s = rsqI8[nu], t1s = rsqI8[np], t2s = rsqI8[nn];
    float2 h3u = make_float2(g0.x*t0s, g0.y*t0s);
    float2 h3p = make_float2(g1.x*t1s, g1.y*t1s);
    float2 h3n = make_float2(g2.x*t2s, g2.y*t2s);

    // --- score epilogue ---
    float2 e0u, e0p, e0n;
    if(l < 32){
        e0u = ei[(size_t)nu*32 + l]; e0p = ei[(size_t)np*32 + l]; e0n = ei[(size_t)nn*32 + l];
    } else {
        e0u = ep[(size_t)nu*32 + (l-32)]; e0p = ep[(size_t)np*32 + (l-32)]; e0n = ep[(size_t)nn*32 + (l-32)];
    }
    v2f h1u = fp8x2_to_f32(h1C[(size_t)(nu+1)*64 + l]);
    v2f h1p = fp8x2_to_f32(h1C[(size_t)(np+1)*64 + l]);
    v2f h1n = fp8x2_to_f32(h1C[(size_t)(nn+1)*64 + l]);
    v2f h2u = fp8x2_to_f32(h2C[(size_t)(nu+1)*64 + l]);
    v2f h2p = fp8x2_to_f32(h2C[(size_t)(np+1)*64 + l]);
    v2f h2n = fp8x2_to_f32(h2C[(size_t)(nn+1)*64 + l]);

    float squ = sqd[nu], sqp = sqd[np], sqn = sqd[nn];  // sqrt(deg)/8: unscales stored h1+h2

    float fux = e0u.x + squ*(h1u.x + h2u.x) + h3u.x, fuy = e0u.y + squ*(h1u.y + h2u.y) + h3u.y;
    float fpx = e0p.x + sqp*(h1p.x + h2p.x) + h3p.x, fpy = e0p.y + sqp*(h1p.y + h2p.y) + h3p.y;
    float fnx = e0n.x + sqn*(h1n.x + h2n.x) + h3n.x, fny = e0n.y + sqn*(h1n.y + h2n.y) + h3n.y;

    float dp = fux*fpx + fuy*fpy;
    float dn = fux*fnx + fuy*fny;
    for(int off=16; off; off>>=1){ dp += __shfl_down(dp,off,32); dn += __shfl_down(dn,off,32); }
    float pi  = __shfl(dp, 0, 64) * (1.f/16.f);
    float ni  = __shfl(dn, 0, 64) * (1.f/16.f);
    float pp  = __shfl(dp, 32, 64) * (1.f/16.f);
    float npp = __shfl(dn, 32, 64) * (1.f/16.f);
    if(l == 0){
        bool bytes = (*mflag)!=0;
        float mf = bytes ? (((const unsigned char*)mask)[b]?1.f:0.f)
                         : (((const int*)mask)[b]?1.f:0.f);
        float nmf = 1.f-mf;
        float a0 = mf  * logsigf(pi-ni);
        float a1 = mf  * logsigf(npp-pp);
        float a2 = nmf * logsigf(pp-npp);
        int ip=item_p[b], in_=item_n[b];
        float popp = softplusf(q[ip]) + softplusf(bq[ip]);
        float popn = softplusf(q[in_]) + softplusf(bq[in_]);
        float a3 = logsigf(tanhf(popp)*(pi+pp) - tanhf(popn)*(ni+npp));
        wsum[wv] = make_float4(a0,a1,a2,a3);
    }
    __syncthreads();
    if(threadIdx.x == 0){
        float4 s0v=wsum[0], s1v=wsum[1], s2v=wsum[2], s3v=wsum[3];
        partial[blockIdx.x] = make_float4(s0v.x+s1v.x+s2v.x+s3v.x, s0v.y+s1v.y+s2v.y+s3v.y,
                                          s0v.z+s1v.z+s2v.z+s3v.z, s0v.w+s1v.w+s2v.w+s3v.w);
    }
}

__global__ __launch_bounds__(256) void k_lossfin(const float4* __restrict__ partial, float* __restrict__ out){
    __shared__ float4 sh[256];
    float4 s = make_float4(0,0,0,0);
    for(int i=threadIdx.x; i<LBLK; i+=256){
        float4 v = partial[i];
        s.x+=v.x; s.y+=v.y; s.z+=v.z; s.w+=v.w;
    }
    sh[threadIdx.x]=s;
    __syncthreads();
    for(int off=128; off; off>>=1){
        if(threadIdx.x < off){
            float4 a=sh[threadIdx.x], b2=sh[threadIdx.x+off];
            sh[threadIdx.x]=make_float4(a.x+b2.x,a.y+b2.y,a.z+b2.z,a.w+b2.w);
        }
        __syncthreads();
    }
    if(threadIdx.x==0){
        const float invB = 1.f/(float)BSZ;
        float4 t = sh[0];
        float loss_int  = -t.x*invB;
        float loss_pop  = -t.y*invB + t.z*invB;
        float loss_tide = -t.w*invB;
        out[0] = 0.1f*loss_int + 0.1f*loss_pop + 0.2f*loss_tide;
    }
}

extern "C" void kernel_launch(void* const* d_in, const int* in_sizes, int n_in,
                              void* d_out, int out_size, void* d_ws, size_t ws_size,
                              hipStream_t stream){
    const float* emb_int = (const float*)d_in[0];
    const float* emb_pop = (const float*)d_in[1];
    const float* q    = (const float*)d_in[2];
    const float* bq   = (const float*)d_in[3];
    const int* user   = (const int*)d_in[4];
    const int* item_p = (const int*)d_in[5];
    const int* item_n = (const int*)d_in[6];
    const void* mask  = d_in[7];
    const int* esrc   = (const int*)d_in[8];
    const int* edst   = (const int*)d_in[9];

    char* ws = (char*)d_ws;
    size_t o = 0;
    auto take = [&](size_t bytes)->char*{ char* p = ws + o; o = (o + bytes + 255) & ~(size_t)255; return p; };
    unsigned* histD = (unsigned*)take((size_t)NB*CB*4);
    unsigned* histS = (unsigned*)take((size_t)NB*CB*4);
    unsigned* ctD   = (unsigned*)take((size_t)CB*4);
    unsigned* ctS   = (unsigned*)take((size_t)CB*4);
    unsigned* bsD   = (unsigned*)take((size_t)(CB+1)*4);
    unsigned* bsS   = (unsigned*)take((size_t)(CB+1)*4);
    unsigned* part  = (unsigned*)take((size_t)NEDGE*4);
    unsigned char* spart = (unsigned char*)take((size_t)NEDGE);
    float*    sqd   = (float*)take((size_t)NNODE*4);
    unsigned* rs    = (unsigned*)take((size_t)NNODE*4);
    unsigned* degI  = (unsigned*)take((size_t)NNODE*4);
    unsigned* ec    = (unsigned*)take((size_t)(NEDGE + BSLACK*CB + 16)*4);  // padded rows
    float*    srow  = (float*)take((size_t)NNODE*4);
    float*    rsqI8 = (float*)take((size_t)NNODE*4);
    unsigned short* hEb  = (unsigned short*)take((size_t)(NNODE+1)*64*2);  // guard row 0
    unsigned short* h1Cb = (unsigned short*)take((size_t)(NNODE+1)*64*2);
    unsigned short* h2Cb = (unsigned short*)take((size_t)(NNODE+1)*64*2);
    float4*   partial = (float4*)take((size_t)LBLK*16);
    unsigned* mflag = (unsigned*)take(256);
    (void)ws_size; (void)in_sizes; (void)n_in; (void)out_size;

    k_hist<<<NB+1,512,0,stream>>>(esrc, edst, histD, histS,
                                  (const unsigned char*)mask, mflag);
    k_colscan<<<dim3(CB,2),512,0,stream>>>(histD, histS, ctD, ctS);
    k_bstart<<<1,1024,0,stream>>>(ctD, ctS, bsD, bsS);
    k_scatter<<<NB,512,0,stream>>>(esrc, edst, histD, histS, bsD, bsS, part, spart);
    k_build<<<CB+1,256,0,stream>>>(spart, bsS, part, bsD,
                                   (const float4*)emb_int, (const float4*)emb_pop,
                                   rs, degI, ec, srow, rsqI8, sqd,
                                   (unsigned*)hEb, (unsigned*)h1Cb, (unsigned*)h2Cb);

    const int spB = ((NNODE/4)*64 + 255)/256;     // one wave per 4 rows
    k_spmm_c<<<spB,256,0,stream>>>(hEb,  h1Cb, rs, degI, ec, srow);  // layer 1
    k_spmm_c<<<spB,256,0,stream>>>(h1Cb, h2Cb, rs, degI, ec, srow);  // layer 2
    k_scoreloss<<<LBLK,256,0,stream>>>((const float2*)emb_int, (const float2*)emb_pop,
                                       h1Cb, h2Cb, rs, degI, ec, rsqI8,
                                       q, bq, user, item_p, item_n,
                                       mask, mflag, sqd, partial);
    k_lossfin<<<1,256,0,stream>>>(partial, (float*)d_out);
}

// Round 14
// 303.229 us; speedup vs baseline: 1.0208x; 1.0208x over previous
//
#include <hip/hip_runtime.h>
#include <hip/hip_bf16.h>
#include <math.h>

#define N_USER 100000
#define N_ITEM 50000
#define NNODE  150000   // N_USER + N_ITEM
#define DIM    64
#define NEDGE  2000000
#define BSZ    8192
#define NTGT   (3*BSZ)
#define CB     586      // ceil(NNODE/256) coarse buckets
#define NB     512      // edge chunks
#define CH     ((NEDGE + NB - 1)/NB)   // 3907
#define LBLK   2048
#define PREPB  (NNODE*32/256)   // 18750 prep blocks (u32 outputs)
#define CAP    5120     // k_dcsr per-bucket LDS capacity
#define BSLACK 772      // per-bucket ec slack for row padding (3*256 + align)

typedef float v2f __attribute__((ext_vector_type(2)));
typedef unsigned v4u __attribute__((ext_vector_type(4)));

__device__ __forceinline__ float logsigf(float x){
    return fminf(x, 0.f) - log1pf(expf(-fabsf(x)));
}
__device__ __forceinline__ float softplusf(float x){
    return fmaxf(x, 0.f) + log1pf(expf(-fabsf(x)));
}
__device__ __forceinline__ v2f fp8x2_to_f32(unsigned short u){
    return __builtin_amdgcn_cvt_pk_f32_fp8((int)u, false);
}
__device__ __forceinline__ unsigned short f32_to_fp8x2(float a, float b){
    return (unsigned short)__builtin_amdgcn_cvt_pk_fp8_f32(a, b, 0, false);
}
__device__ __forceinline__ unsigned rfl(unsigned v){
    return (unsigned)__builtin_amdgcn_readfirstlane((int)v);
}
__device__ __forceinline__ v4u nt4(const unsigned* p){
    return __builtin_nontemporal_load((const v4u*)p);
}
__device__ __forceinline__ unsigned umin2(unsigned a, unsigned b){ return a<b ? a : b; }

// exclusive scan of arr[CB] with 512 threads (each owns 2 slots)
__device__ __forceinline__ void scanCB512(unsigned* arr, unsigned* tmp){
    int t = threadIdx.x;
    int base = 2*t;
    unsigned a0=0,a1=0;
    if(base   < CB) a0 = arr[base];
    if(base+1 < CB) a1 = arr[base+1];
    unsigned s = a0+a1;
    tmp[t]=s; __syncthreads();
    for(int off=1; off<512; off<<=1){
        unsigned v = (t>=off)? tmp[t-off] : 0u;
        __syncthreads();
        tmp[t] += v;
        __syncthreads();
    }
    unsigned excl = tmp[t]-s;
    if(base   < CB) arr[base]   = excl;
    if(base+1 < CB) arr[base+1] = excl+a0;
    __syncthreads();
}

// ==== coarse histograms, both sides, LDS-only ([chunk][bin]) + mask ======
__global__ __launch_bounds__(512) void k_hist(const int* __restrict__ src, const int* __restrict__ dst,
                       unsigned* __restrict__ histD, unsigned* __restrict__ histS,
                       const unsigned char* __restrict__ mask8, unsigned* __restrict__ mflag){
    if(blockIdx.x == NB){
        __shared__ int any;
        if(threadIdx.x==0) any=0;
        __syncthreads();
        for(int i=threadIdx.x;i<BSZ;i+=512){ if((i&3) && mask8[i]) any=1; }
        __syncthreads();
        if(threadIdx.x==0) *mflag = (any!=0) ? 1u : 0u;
        return;
    }
    __shared__ unsigned hD[CB], hS[CB];
    for(int i=threadIdx.x;i<CB;i+=512){ hD[i]=0; hS[i]=0; }
    __syncthreads();
    int lo = blockIdx.x*CH, hi = min(lo+CH, NEDGE);
    for(int e=lo+threadIdx.x; e<hi; e+=512){
        atomicAdd(&hS[src[e]>>8],1u);
        atomicAdd(&hD[dst[e]>>8],1u);
    }
    __syncthreads();
    for(int i=threadIdx.x;i<CB;i+=512){          // contiguous full-line writes
        histD[(size_t)blockIdx.x*CB + i]=hD[i];
        histS[(size_t)blockIdx.x*CB + i]=hS[i];
    }
}

// scan along chunks for each bucket; strided access into L2-resident array
__global__ __launch_bounds__(512) void k_colscan(unsigned* __restrict__ histD, unsigned* __restrict__ histS,
                          unsigned* __restrict__ ctD, unsigned* __restrict__ ctS){
    unsigned* hist = blockIdx.y ? histS : histD;
    unsigned* ct   = blockIdx.y ? ctS   : ctD;
    int b = blockIdx.x;
    __shared__ unsigned sh[512];
    unsigned v = hist[(size_t)threadIdx.x*CB + b];
    sh[threadIdx.x] = v;
    __syncthreads();
    for(int off=1; off<512; off<<=1){
        unsigned t = (threadIdx.x>=off)? sh[threadIdx.x-off] : 0u;
        __syncthreads();
        sh[threadIdx.x] += t;
        __syncthreads();
    }
    hist[(size_t)threadIdx.x*CB + b] = sh[threadIdx.x] - v;
    if(threadIdx.x==511) ct[b] = sh[511];
}

__global__ __launch_bounds__(1024) void k_bstart(const unsigned* __restrict__ ctD, const unsigned* __restrict__ ctS,
                         unsigned* __restrict__ bsD, unsigned* __restrict__ bsS){
    __shared__ unsigned sh[1024];
    unsigned v = (threadIdx.x<CB)? ctD[threadIdx.x] : 0u;
    sh[threadIdx.x]=v; __syncthreads();
    for(int off=1; off<1024; off<<=1){ unsigned t=(threadIdx.x>=off)?sh[threadIdx.x-off]:0u; __syncthreads(); sh[threadIdx.x]+=t; __syncthreads(); }
    if(threadIdx.x<CB) bsD[threadIdx.x]=sh[threadIdx.x]-v;
    if(threadIdx.x==CB-1) bsD[CB]=sh[threadIdx.x];
    __syncthreads();
    unsigned v2 = (threadIdx.x<CB)? ctS[threadIdx.x] : 0u;
    sh[threadIdx.x]=v2; __syncthreads();
    for(int off=1; off<1024; off<<=1){ unsigned t=(threadIdx.x>=off)?sh[threadIdx.x-off]:0u; __syncthreads(); sh[threadIdx.x]+=t; __syncthreads(); }
    if(threadIdx.x<CB) bsS[threadIdx.x]=sh[threadIdx.x]-v2;
    if(threadIdx.x==CB-1) bsS[CB]=sh[threadIdx.x];
}

// ==== scatter with LDS reorder, 512 threads ==============================
__global__ __launch_bounds__(512) void k_scatter(const int* __restrict__ src, const int* __restrict__ dst,
                          const unsigned* __restrict__ histD, const unsigned* __restrict__ histS,
                          const unsigned* __restrict__ bsD, const unsigned* __restrict__ bsS,
                          unsigned* __restrict__ part, unsigned char* __restrict__ spart){
    __shared__ unsigned curD[CB], curS[CB];
    __shared__ unsigned lhD[CB], lhS[CB];
    __shared__ unsigned startD[CB], startS[CB];
    __shared__ unsigned tmp[512];
    __shared__ unsigned partl[CH];
    __shared__ unsigned short keyD[CH];
    __shared__ unsigned short keyS[CH];
    __shared__ unsigned char sl[CH];
    for(int i=threadIdx.x;i<CB;i+=512){
        curD[i]=bsD[i]+histD[(size_t)blockIdx.x*CB+i];
        curS[i]=bsS[i]+histS[(size_t)blockIdx.x*CB+i];
        lhD[i]=0; lhS[i]=0;
    }
    __syncthreads();
    int lo=blockIdx.x*CH, hi=min(lo+CH,NEDGE);
    int n = hi-lo;
    for(int e=lo+threadIdx.x;e<hi;e+=512){
        atomicAdd(&lhD[dst[e]>>8],1u);
        atomicAdd(&lhS[src[e]>>8],1u);
    }
    __syncthreads();
    scanCB512(lhD, tmp);
    scanCB512(lhS, tmp);
    for(int i=threadIdx.x;i<CB;i+=512){ startD[i]=lhD[i]; startS[i]=lhS[i]; }
    __syncthreads();
    for(int e=lo+threadIdx.x;e<hi;e+=512){
        int s=src[e], d=dst[e];
        unsigned bd=(unsigned)(d>>8);
        unsigned slot=atomicAdd(&lhD[bd],1u);
        partl[slot]=((unsigned)(d&255)<<18)|(unsigned)s;
        keyD[slot]=(unsigned short)bd;
        unsigned bs=(unsigned)(s>>8);
        unsigned sslot=atomicAdd(&lhS[bs],1u);
        sl[sslot]=(unsigned char)(s&255);
        keyS[sslot]=(unsigned short)bs;
    }
    __syncthreads();
    for(int k=threadIdx.x;k<n;k+=512){
        unsigned b=keyD[k];
        part[curD[b] + (unsigned)k - startD[b]] = partl[k];
    }
    for(int k=threadIdx.x;k<n;k+=512){
        unsigned b=keyS[k];
        spart[curS[b] + (unsigned)k - startS[b]] = sl[k];
    }
}

// ==== fused per-bucket degO + csr (matching CB-grid parallelism) =========
__global__ __launch_bounds__(256) void k_dcsr(const unsigned char* __restrict__ spart, const unsigned* __restrict__ bsS,
                      const unsigned* __restrict__ part, const unsigned* __restrict__ bsD,
                      unsigned* __restrict__ rs, unsigned* __restrict__ degI,
                      unsigned* __restrict__ ec, float* __restrict__ srow, float* __restrict__ rsqI8,
                      float* __restrict__ rsqO, float* __restrict__ sqd){
    __shared__ unsigned cnt[256], cur[256], sh[256];
    __shared__ unsigned stR[256], exR[256];
    __shared__ float rsqOl[256];
    __shared__ unsigned partl[CAP];
    int tid = threadIdx.x;
    int node=(blockIdx.x<<8)+tid;
    // --- phase 1: out-degree ---
    cnt[tid]=0; __syncthreads();
    {
        unsigned slo=bsS[blockIdx.x], shi=bsS[blockIdx.x+1];
        for(unsigned e=slo+tid;e<shi;e+=256) atomicAdd(&cnt[spart[e]],1u);
    }
    __syncthreads();
    {
        float dv = fmaxf((float)cnt[tid],1.f);
        float r = rsqrtf(dv);
        rsqOl[tid]=r;
        if(node<NNODE){
            rsqO[node]=r;                       // for wide k_prep
            sqd[node]=sqrtf(dv)*0.125f;         // (1/rsqO)/8 for scoreloss
        }
    }
    __syncthreads();
    // --- phase 2: csr (padded rows, guard edges) ---
    cnt[tid]=0; __syncthreads();
    unsigned lo=bsD[blockIdx.x], hi=bsD[blockIdx.x+1];
    unsigned n = hi-lo;
    for(unsigned e=lo+tid;e<hi;e+=256) atomicAdd(&cnt[part[e]>>18],1u);
    __syncthreads();
    unsigned c=cnt[tid];
    unsigned r4=(c+3u)&~3u;
    sh[tid]=c; __syncthreads();
    for(int o=1;o<256;o<<=1){ unsigned t2=(tid>=o)?sh[tid-o]:0u; __syncthreads(); sh[tid]+=t2; __syncthreads(); }
    unsigned ex = sh[tid]-c;
    __syncthreads();
    sh[tid]=r4; __syncthreads();
    for(int o=1;o<256;o<<=1){ unsigned t2=(tid>=o)?sh[tid-o]:0u; __syncthreads(); sh[tid]+=t2; __syncthreads(); }
    unsigned ex_r = sh[tid]-r4;
    stR[tid]=ex; exR[tid]=ex_r;
    cur[tid]=(n<=CAP)? ex : ex_r;
    unsigned lo_ec = ((lo+3u)&~3u) + (unsigned)BSLACK*blockIdx.x;
    if(node<NNODE){
        degI[node]=r4; rs[node]=lo_ec+ex_r;
        float rI = rsqrtf(fmaxf((float)c,1.f));   // REAL in-degree for norm
        srow[node]  = rI*rsqOl[tid];   // 8-factors cancel
        rsqI8[node] = rI*0.125f;       // layer-3 epilogue scale
    }
    for(unsigned j=c;j<r4;++j) ec[lo_ec+ex_r+j]=0u;   // guard-fill pads
    __syncthreads();
    if(n <= CAP){
        for(unsigned e=lo+tid;e<hi;e+=256){
            unsigned p=part[e];
            unsigned slot=atomicAdd(&cur[p>>18],1u);
            partl[slot]=p;
        }
        __syncthreads();
        for(unsigned k=tid;k<n;k+=256){
            unsigned p=partl[k];
            unsigned fb=p>>18;
            ec[lo_ec + exR[fb] + (k - stR[fb])] = ((p&0x3FFFFu)+1u)<<7;
        }
    } else {
        for(unsigned e=lo+tid;e<hi;e+=256){
            unsigned p=part[e];
            unsigned pos=lo_ec+atomicAdd(&cur[p>>18],1u);
            ec[pos] = ((p&0x3FFFFu)+1u)<<7;
        }
    }
}

// ==== fp8 prep with 8*rsqO pre-scale + guard rows (wide grid) ============
__global__ __launch_bounds__(256) void k_prep(const float4* __restrict__ ei, const float4* __restrict__ ep,
                      const float* __restrict__ rsqO,
                      unsigned* __restrict__ hE32, unsigned* __restrict__ h1g, unsigned* __restrict__ h2g){
    if(blockIdx.x == PREPB){
        int t = threadIdx.x;
        if(t < 32) hE32[t] = 0u;              // guard row: fp8 zeros
        else if(t < 64) h1g[t-32] = 0u;
        else if(t < 96) h2g[t-64] = 0u;
        return;
    }
    int idx = blockIdx.x*256 + threadIdx.x;
    int n = idx>>5, c = idx&31;
    float sc = 8.f*rsqO[n];                   // stored = 8*rsqO*h  (keeps e4m3 in normal range)
    float4 v;
    if(c<16) v = ei[(size_t)n*16 + c];
    else     v = ep[(size_t)n*16 + (c-16)];
    int d = __builtin_amdgcn_cvt_pk_fp8_f32(v.x*sc, v.y*sc, 0, false);
    d = __builtin_amdgcn_cvt_pk_fp8_f32(v.z*sc, v.w*sc, d, true);
    hE32[32 + (size_t)n*32 + c] = (unsigned)d;   // +32 dwords skips guard row
}

// ==== SpMM: 4 rows/wave joint loop + rotating e-prefetch =================
__device__ __forceinline__ void drain4(const char* __restrict__ hb,
                                       const unsigned* __restrict__ ec,
                                       unsigned s, unsigned c, unsigned &i, unsigned lane2,
                                       v2f &acc){
    for(; i+4<=c; i+=4){
        v4u e = nt4(&ec[s+i]);
        unsigned short u0=*(const unsigned short*)(hb+e.x+lane2);
        unsigned short u1=*(const unsigned short*)(hb+e.y+lane2);
        unsigned short u2=*(const unsigned short*)(hb+e.z+lane2);
        unsigned short u3=*(const unsigned short*)(hb+e.w+lane2);
        acc += fp8x2_to_f32(u0); acc += fp8x2_to_f32(u1);
        acc += fp8x2_to_f32(u2); acc += fp8x2_to_f32(u3);
    }
}

__global__ __launch_bounds__(256) void k_spmm_c(const unsigned short* __restrict__ hinb, unsigned short* __restrict__ houtb,
                                                const unsigned* __restrict__ rs, const unsigned* __restrict__ degI,
                                                const unsigned* __restrict__ ec, const float* __restrict__ srow){
    int wv = (blockIdx.x*256 + threadIdx.x) >> 6;
    int lane = threadIdx.x & 63;
    int r = 4*wv;                         // NNODE % 4 == 0, natural order
    if(r >= NNODE) return;
    unsigned s0=rfl(rs[r  ]), c0=rfl(degI[r  ]);
    unsigned s1=rfl(rs[r+1]), c1=rfl(degI[r+1]);
    unsigned s2=rfl(rs[r+2]), c2=rfl(degI[r+2]);
    unsigned s3=rfl(rs[r+3]), c3=rfl(degI[r+3]);
    const char* hb = (const char*)hinb;
    unsigned lane2 = ((unsigned)lane)*2u;
    v2f a0={0.f,0.f}, a1={0.f,0.f}, a2={0.f,0.f}, a3={0.f,0.f};
    unsigned m = umin2(umin2(c0,c1), umin2(c2,c3));   // multiple of 4
    v4u eA, eB, eC, eD;
    if(m){
        eA=nt4(&ec[s0]); eB=nt4(&ec[s1]); eC=nt4(&ec[s2]); eD=nt4(&ec[s3]);
    }
    for(unsigned i=0; i<m; i+=4){
        unsigned ip = (i+4<m) ? i+4 : 0u;            // clamped: last iter reloads offset 0
        v4u fA=nt4(&ec[s0+ip]), fB=nt4(&ec[s1+ip]), fC=nt4(&ec[s2+ip]), fD=nt4(&ec[s3+ip]);
        unsigned short u00=*(const unsigned short*)(hb+eA.x+lane2);
        unsigned short u01=*(const unsigned short*)(hb+eA.y+lane2);
        unsigned short u02=*(const unsigned short*)(hb+eA.z+lane2);
        unsigned short u03=*(const unsigned short*)(hb+eA.w+lane2);
        unsigned short u10=*(const unsigned short*)(hb+eB.x+lane2);
        unsigned short u11=*(const unsigned short*)(hb+eB.y+lane2);
        unsigned short u12=*(const unsigned short*)(hb+eB.z+lane2);
        unsigned short u13=*(const unsigned short*)(hb+eB.w+lane2);
        unsigned short u20=*(const unsigned short*)(hb+eC.x+lane2);
        unsigned short u21=*(const unsigned short*)(hb+eC.y+lane2);
        unsigned short u22=*(const unsigned short*)(hb+eC.z+lane2);
        unsigned short u23=*(const unsigned short*)(hb+eC.w+lane2);
        unsigned short u30=*(const unsigned short*)(hb+eD.x+lane2);
        unsigned short u31=*(const unsigned short*)(hb+eD.y+lane2);
        unsigned short u32v=*(const unsigned short*)(hb+eD.z+lane2);
        unsigned short u33=*(const unsigned short*)(hb+eD.w+lane2);
        a0 += fp8x2_to_f32(u00); a0 += fp8x2_to_f32(u01); a0 += fp8x2_to_f32(u02); a0 += fp8x2_to_f32(u03);
        a1 += fp8x2_to_f32(u10); a1 += fp8x2_to_f32(u11); a1 += fp8x2_to_f32(u12); a1 += fp8x2_to_f32(u13);
        a2 += fp8x2_to_f32(u20); a2 += fp8x2_to_f32(u21); a2 += fp8x2_to_f32(u22); a2 += fp8x2_to_f32(u23);
        a3 += fp8x2_to_f32(u30); a3 += fp8x2_to_f32(u31); a3 += fp8x2_to_f32(u32v); a3 += fp8x2_to_f32(u33);
        eA=fA; eB=fB; eC=fC; eD=fD;
    }
    unsigned i0=m,i1=m,i2=m,i3=m;
    drain4(hb, ec, s0, c0, i0, lane2, a0);
    drain4(hb, ec, s1, c1, i1, lane2, a1);
    drain4(hb, ec, s2, c2, i2, lane2, a2);
    drain4(hb, ec, s3, c3, i3, lane2, a3);
    float sc0=srow[r], sc1=srow[r+1], sc2=srow[r+2], sc3=srow[r+3];
    houtb[(size_t)(r+1)*64+lane] = f32_to_fp8x2(sc0*a0.x, sc0*a0.y);
    houtb[(size_t)(r+2)*64+lane] = f32_to_fp8x2(sc1*a1.x, sc1*a1.y);
    houtb[(size_t)(r+3)*64+lane] = f32_to_fp8x2(sc2*a2.x, sc2*a2.y);
    houtb[(size_t)(r+4)*64+lane] = f32_to_fp8x2(sc3*a3.x, sc3*a3.y);
}

// ==== fused layer-3 gather + score + loss: one wave per sample ===========
__global__ __launch_bounds__(256) void k_scoreloss(const float2* __restrict__ ei, const float2* __restrict__ ep,
                        const unsigned short* __restrict__ h1C, const unsigned short* __restrict__ h2C,
                        const unsigned* __restrict__ rs, const unsigned* __restrict__ degI,
                        const unsigned* __restrict__ ec, const float* __restrict__ rsqI8,
                        const float* __restrict__ q, const float* __restrict__ bq,
                        const int* __restrict__ user, const int* __restrict__ item_p, const int* __restrict__ item_n,
                        const void* __restrict__ mask, const unsigned* __restrict__ mflag,
                        const float* __restrict__ sqd,
                        float4* __restrict__ partial){
    int t = blockIdx.x*256 + threadIdx.x;
    int b = t >> 6, l = t & 63;
    int wv = threadIdx.x >> 6;
    __shared__ float4 wsum[4];
    int nu = __builtin_amdgcn_readfirstlane(user[b]);
    int np = __builtin_amdgcn_readfirstlane(item_p[b]) + N_USER;
    int nn = __builtin_amdgcn_readfirstlane(item_n[b]) + N_USER;

    // --- in-wave layer-3 gather over h2C for the 3 target rows ---
    unsigned s0 = rfl(rs[nu]), c0 = rfl(degI[nu]);
    unsigned s1 = rfl(rs[np]), c1 = rfl(degI[np]);
    unsigned s2 = rfl(rs[nn]), c2 = rfl(degI[nn]);
    const char* hb = (const char*)h2C;
    unsigned lane2 = ((unsigned)l)*2u;
    v2f g0={0.f,0.f}, g1={0.f,0.f}, g2={0.f,0.f};
    unsigned m = umin2(umin2(c0,c1), c2);
    for(unsigned i=0; i<m; i+=4){
        v4u eA=nt4(&ec[s0+i]), eB=nt4(&ec[s1+i]), eC=nt4(&ec[s2+i]);
        unsigned short u0=*(const unsigned short*)(hb+eA.x+lane2);
        unsigned short u1=*(const unsigned short*)(hb+eA.y+lane2);
        unsigned short u2=*(const unsigned short*)(hb+eA.z+lane2);
        unsigned short u3=*(const unsigned short*)(hb+eA.w+lane2);
        unsigned short u4=*(const unsigned short*)(hb+eB.x+lane2);
        unsigned short u5=*(const unsigned short*)(hb+eB.y+lane2);
        unsigned short u6=*(const unsigned short*)(hb+eB.z+lane2);
        unsigned short u7=*(const unsigned short*)(hb+eB.w+lane2);
        unsigned short u8=*(const unsigned short*)(hb+eC.x+lane2);
        unsigned short u9=*(const unsigned short*)(hb+eC.y+lane2);
        unsigned short ua=*(const unsigned short*)(hb+eC.z+lane2);
        unsigned short ub=*(const unsigned short*)(hb+eC.w+lane2);
        g0 += fp8x2_to_f32(u0); g0 += fp8x2_to_f32(u1); g0 += fp8x2_to_f32(u2); g0 += fp8x2_to_f32(u3);
        g1 += fp8x2_to_f32(u4); g1 += fp8x2_to_f32(u5); g1 += fp8x2_to_f32(u6); g1 += fp8x2_to_f32(u7);
        g2 += fp8x2_to_f32(u8); g2 += fp8x2_to_f32(u9); g2 += fp8x2_to_f32(ua); g2 += fp8x2_to_f32(ub);
    }
    unsigned i0=m, i1=m, i2=m;
    drain4(hb, ec, s0, c0, i0, lane2, g0);
    drain4(hb, ec, s1, c1, i1, lane2, g1);
    drain4(hb, ec, s2, c2, i2, lane2, g2);
    float t0s = rsqI8[nu], t1s = rsqI8[np], t2s = rsqI8[nn];
    float2 h3u = make_float2(g0.x*t0s, g0.y*t0s);
    float2 h3p = make_float2(g1.x*t1s, g1.y*t1s);
    float2 h3n = make_float2(g2.x*t2s, g2.y*t2s);

    // --- score epilogue ---
    float2 e0u, e0p, e0n;
    if(l < 32){
        e0u = ei[(size_t)nu*32 + l]; e0p = ei[(size_t)np*32 + l]; e0n = ei[(size_t)nn*32 + l];
    } else {
        e0u = ep[(size_t)nu*32 + (l-32)]; e0p = ep[(size_t)np*32 + (l-32)]; e0n = ep[(size_t)nn*32 + (l-32)];
    }
    v2f h1u = fp8x2_to_f32(h1C[(size_t)(nu+1)*64 + l]);
    v2f h1p = fp8x2_to_f32(h1C[(size_t)(np+1)*64 + l]);
    v2f h1n = fp8x2_to_f32(h1C[(size_t)(nn+1)*64 + l]);
    v2f h2u = fp8x2_to_f32(h2C[(size_t)(nu+1)*64 + l]);
    v2f h2p = fp8x2_to_f32(h2C[(size_t)(np+1)*64 + l]);
    v2f h2n = fp8x2_to_f32(h2C[(size_t)(nn+1)*64 + l]);

    float squ = sqd[nu], sqp = sqd[np], sqn = sqd[nn];  // sqrt(deg)/8: unscales stored h1+h2

    float fux = e0u.x + squ*(h1u.x + h2u.x) + h3u.x, fuy = e0u.y + squ*(h1u.y + h2u.y) + h3u.y;
    float fpx = e0p.x + sqp*(h1p.x + h2p.x) + h3p.x, fpy = e0p.y + sqp*(h1p.y + h2p.y) + h3p.y;
    float fnx = e0n.x + sqn*(h1n.x + h2n.x) + h3n.x, fny = e0n.y + sqn*(h1n.y + h2n.y) + h3n.y;

    float dp = fux*fpx + fuy*fpy;
    float dn = fux*fnx + fuy*fny;
    for(int off=16; off; off>>=1){ dp += __shfl_down(dp,off,32); dn += __shfl_down(dn,off,32); }
    float pi  = __shfl(dp, 0, 64) * (1.f/16.f);
    float ni  = __shfl(dn, 0, 64) * (1.f/16.f);
    float pp  = __shfl(dp, 32, 64) * (1.f/16.f);
    float npp = __shfl(dn, 32, 64) * (1.f/16.f);
    if(l == 0){
        bool bytes = (*mflag)!=0;
        float mf = bytes ? (((const unsigned char*)mask)[b]?1.f:0.f)
                         : (((const int*)mask)[b]?1.f:0.f);
        float nmf = 1.f-mf;
        float a0 = mf  * logsigf(pi-ni);
        float a1 = mf  * logsigf(npp-pp);
        float a2 = nmf * logsigf(pp-npp);
        int ip=item_p[b], in_=item_n[b];
        float popp = softplusf(q[ip]) + softplusf(bq[ip]);
        float popn = softplusf(q[in_]) + softplusf(bq[in_]);
        float a3 = logsigf(tanhf(popp)*(pi+pp) - tanhf(popn)*(ni+npp));
        wsum[wv] = make_float4(a0,a1,a2,a3);
    }
    __syncthreads();
    if(threadIdx.x == 0){
        float4 s0v=wsum[0], s1v=wsum[1], s2v=wsum[2], s3v=wsum[3];
        partial[blockIdx.x] = make_float4(s0v.x+s1v.x+s2v.x+s3v.x, s0v.y+s1v.y+s2v.y+s3v.y,
                                          s0v.z+s1v.z+s2v.z+s3v.z, s0v.w+s1v.w+s2v.w+s3v.w);
    }
}

__global__ __launch_bounds__(256) void k_lossfin(const float4* __restrict__ partial, float* __restrict__ out){
    __shared__ float4 sh[256];
    float4 s = make_float4(0,0,0,0);
    for(int i=threadIdx.x; i<LBLK; i+=256){
        float4 v = partial[i];
        s.x+=v.x; s.y+=v.y; s.z+=v.z; s.w+=v.w;
    }
    sh[threadIdx.x]=s;
    __syncthreads();
    for(int off=128; off; off>>=1){
        if(threadIdx.x < off){
            float4 a=sh[threadIdx.x], b2=sh[threadIdx.x+off];
            sh[threadIdx.x]=make_float4(a.x+b2.x,a.y+b2.y,a.z+b2.z,a.w+b2.w);
        }
        __syncthreads();
    }
    if(threadIdx.x==0){
        const float invB = 1.f/(float)BSZ;
        float4 t = sh[0];
        float loss_int  = -t.x*invB;
        float loss_pop  = -t.y*invB + t.z*invB;
        float loss_tide = -t.w*invB;
        out[0] = 0.1f*loss_int + 0.1f*loss_pop + 0.2f*loss_tide;
    }
}

extern "C" void kernel_launch(void* const* d_in, const int* in_sizes, int n_in,
                              void* d_out, int out_size, void* d_ws, size_t ws_size,
                              hipStream_t stream){
    const float* emb_int = (const float*)d_in[0];
    const float* emb_pop = (const float*)d_in[1];
    const float* q    = (const float*)d_in[2];
    const float* bq   = (const float*)d_in[3];
    const int* user   = (const int*)d_in[4];
    const int* item_p = (const int*)d_in[5];
    const int* item_n = (const int*)d_in[6];
    const void* mask  = d_in[7];
    const int* esrc   = (const int*)d_in[8];
    const int* edst   = (const int*)d_in[9];

    char* ws = (char*)d_ws;
    size_t o = 0;
    auto take = [&](size_t bytes)->char*{ char* p = ws + o; o = (o + bytes + 255) & ~(size_t)255; return p; };
    unsigned* histD = (unsigned*)take((size_t)NB*CB*4);
    unsigned* histS = (unsigned*)take((size_t)NB*CB*4);
    unsigned* ctD   = (unsigned*)take((size_t)CB*4);
    unsigned* ctS   = (unsigned*)take((size_t)CB*4);
    unsigned* bsD   = (unsigned*)take((size_t)(CB+1)*4);
    unsigned* bsS   = (unsigned*)take((size_t)(CB+1)*4);
    unsigned* part  = (unsigned*)take((size_t)NEDGE*4);
    unsigned char* spart = (unsigned char*)take((size_t)NEDGE);
    float*    rsqO  = (float*)take((size_t)NNODE*4);
    float*    sqd   = (float*)take((size_t)NNODE*4);
    unsigned* rs    = (unsigned*)take((size_t)NNODE*4);
    unsigned* degI  = (unsigned*)take((size_t)NNODE*4);
    unsigned* ec    = (unsigned*)take((size_t)(NEDGE + BSLACK*CB + 16)*4);  // padded rows
    float*    srow  = (float*)take((size_t)NNODE*4);
    float*    rsqI8 = (float*)take((size_t)NNODE*4);
    unsigned short* hEb  = (unsigned short*)take((size_t)(NNODE+1)*64*2);  // guard row 0
    unsigned short* h1Cb = (unsigned short*)take((size_t)(NNODE+1)*64*2);
    unsigned short* h2Cb = (unsigned short*)take((size_t)(NNODE+1)*64*2);
    float4*   partial = (float4*)take((size_t)LBLK*16);
    unsigned* mflag = (unsigned*)take(256);
    (void)ws_size; (void)in_sizes; (void)n_in; (void)out_size;

    k_hist<<<NB+1,512,0,stream>>>(esrc, edst, histD, histS,
                                  (const unsigned char*)mask, mflag);
    k_colscan<<<dim3(CB,2),512,0,stream>>>(histD, histS, ctD, ctS);
    k_bstart<<<1,1024,0,stream>>>(ctD, ctS, bsD, bsS);
    k_scatter<<<NB,512,0,stream>>>(esrc, edst, histD, histS, bsD, bsS, part, spart);
    k_dcsr<<<CB,256,0,stream>>>(spart, bsS, part, bsD,
                                rs, degI, ec, srow, rsqI8, rsqO, sqd);
    k_prep<<<PREPB+1,256,0,stream>>>((const float4*)emb_int, (const float4*)emb_pop, rsqO,
                                     (unsigned*)hEb, (unsigned*)h1Cb, (unsigned*)h2Cb);

    const int spB = ((NNODE/4)*64 + 255)/256;     // one wave per 4 rows
    k_spmm_c<<<spB,256,0,stream>>>(hEb,  h1Cb, rs, degI, ec, srow);  // layer 1
    k_spmm_c<<<spB,256,0,stream>>>(h1Cb, h2Cb, rs, degI, ec, srow);  // layer 2
    k_scoreloss<<<LBLK,256,0,stream>>>((const float2*)emb_int, (const float2*)emb_pop,
                                       h1Cb, h2Cb, rs, degI, ec, rsqI8,
                                       q, bq, user, item_p, item_n,
                                       mask, mflag, sqd, partial);
    k_lossfin<<<1,256,0,stream>>>(partial, (float*)d_out);
}

// Round 15
// 298.166 us; speedup vs baseline: 1.0382x; 1.0170x over previous
//
#include <hip/hip_runtime.h>
#include <hip/hip_bf16.h>
#include <math.h>

#define N_USER 100000
#define N_ITEM 50000
#define NNODE  150000   // N_USER + N_ITEM
#define DIM    64
#define NEDGE  2000000
#define BSZ    8192
#define NTGT   (3*BSZ)
#define CB     586      // ceil(NNODE/256) coarse buckets
#define NB     512      // edge chunks
#define CH     ((NEDGE + NB - 1)/NB)   // 3907
#define LBLK   2048
#define PREPB  (NNODE*32/256)   // 18750 prep blocks (u32 outputs)
#define CAP    5120     // k_dcsr per-bucket LDS capacity
#define BSLACK 772      // per-bucket ec slack for row padding (3*256 + align)

typedef float v2f __attribute__((ext_vector_type(2)));
typedef unsigned v4u __attribute__((ext_vector_type(4)));

__device__ __forceinline__ float logsigf(float x){
    return fminf(x, 0.f) - log1pf(expf(-fabsf(x)));
}
__device__ __forceinline__ float softplusf(float x){
    return fmaxf(x, 0.f) + log1pf(expf(-fabsf(x)));
}
__device__ __forceinline__ v2f fp8x2_to_f32(unsigned short u){
    return __builtin_amdgcn_cvt_pk_f32_fp8((int)u, false);
}
__device__ __forceinline__ unsigned short f32_to_fp8x2(float a, float b){
    return (unsigned short)__builtin_amdgcn_cvt_pk_fp8_f32(a, b, 0, false);
}
__device__ __forceinline__ unsigned rfl(unsigned v){
    return (unsigned)__builtin_amdgcn_readfirstlane((int)v);
}
__device__ __forceinline__ v4u nt4(const unsigned* p){
    return __builtin_nontemporal_load((const v4u*)p);
}
__device__ __forceinline__ unsigned umin2(unsigned a, unsigned b){ return a<b ? a : b; }

// exclusive scan of arr[CB] with 512 threads (each owns 2 slots)
__device__ __forceinline__ void scanCB512(unsigned* arr, unsigned* tmp){
    int t = threadIdx.x;
    int base = 2*t;
    unsigned a0=0,a1=0;
    if(base   < CB) a0 = arr[base];
    if(base+1 < CB) a1 = arr[base+1];
    unsigned s = a0+a1;
    tmp[t]=s; __syncthreads();
    for(int off=1; off<512; off<<=1){
        unsigned v = (t>=off)? tmp[t-off] : 0u;
        __syncthreads();
        tmp[t] += v;
        __syncthreads();
    }
    unsigned excl = tmp[t]-s;
    if(base   < CB) arr[base]   = excl;
    if(base+1 < CB) arr[base+1] = excl+a0;
    __syncthreads();
}

// ==== coarse histograms, both sides, LDS-only ([chunk][bin]) + mask ======
__global__ __launch_bounds__(512) void k_hist(const int* __restrict__ src, const int* __restrict__ dst,
                       unsigned* __restrict__ histD, unsigned* __restrict__ histS,
                       const unsigned char* __restrict__ mask8, unsigned* __restrict__ mflag){
    if(blockIdx.x == NB){
        __shared__ int any;
        if(threadIdx.x==0) any=0;
        __syncthreads();
        for(int i=threadIdx.x;i<BSZ;i+=512){ if((i&3) && mask8[i]) any=1; }
        __syncthreads();
        if(threadIdx.x==0) *mflag = (any!=0) ? 1u : 0u;
        return;
    }
    __shared__ unsigned hD[CB], hS[CB];
    for(int i=threadIdx.x;i<CB;i+=512){ hD[i]=0; hS[i]=0; }
    __syncthreads();
    int lo = blockIdx.x*CH, hi = min(lo+CH, NEDGE);
    for(int e=lo+threadIdx.x; e<hi; e+=512){
        atomicAdd(&hS[src[e]>>8],1u);
        atomicAdd(&hD[dst[e]>>8],1u);
    }
    __syncthreads();
    for(int i=threadIdx.x;i<CB;i+=512){          // contiguous full-line writes
        histD[(size_t)blockIdx.x*CB + i]=hD[i];
        histS[(size_t)blockIdx.x*CB + i]=hS[i];
    }
}

// scan along chunks for each bucket; writes scans to SEPARATE arrays so
// raw per-chunk counts in hist* stay available for k_scatter's local hist.
__global__ __launch_bounds__(512) void k_colscan(const unsigned* __restrict__ histD, const unsigned* __restrict__ histS,
                          unsigned* __restrict__ scanD, unsigned* __restrict__ scanS,
                          unsigned* __restrict__ ctD, unsigned* __restrict__ ctS){
    const unsigned* hist = blockIdx.y ? histS : histD;
    unsigned* scn  = blockIdx.y ? scanS : scanD;
    unsigned* ct   = blockIdx.y ? ctS   : ctD;
    int b = blockIdx.x;
    __shared__ unsigned sh[512];
    unsigned v = hist[(size_t)threadIdx.x*CB + b];
    sh[threadIdx.x] = v;
    __syncthreads();
    for(int off=1; off<512; off<<=1){
        unsigned t = (threadIdx.x>=off)? sh[threadIdx.x-off] : 0u;
        __syncthreads();
        sh[threadIdx.x] += t;
        __syncthreads();
    }
    scn[(size_t)threadIdx.x*CB + b] = sh[threadIdx.x] - v;
    if(threadIdx.x==511) ct[b] = sh[511];
}

__global__ __launch_bounds__(1024) void k_bstart(const unsigned* __restrict__ ctD, const unsigned* __restrict__ ctS,
                         unsigned* __restrict__ bsD, unsigned* __restrict__ bsS){
    __shared__ unsigned sh[1024];
    unsigned v = (threadIdx.x<CB)? ctD[threadIdx.x] : 0u;
    sh[threadIdx.x]=v; __syncthreads();
    for(int off=1; off<1024; off<<=1){ unsigned t=(threadIdx.x>=off)?sh[threadIdx.x-off]:0u; __syncthreads(); sh[threadIdx.x]+=t; __syncthreads(); }
    if(threadIdx.x<CB) bsD[threadIdx.x]=sh[threadIdx.x]-v;
    if(threadIdx.x==CB-1) bsD[CB]=sh[threadIdx.x];
    __syncthreads();
    unsigned v2 = (threadIdx.x<CB)? ctS[threadIdx.x] : 0u;
    sh[threadIdx.x]=v2; __syncthreads();
    for(int off=1; off<1024; off<<=1){ unsigned t=(threadIdx.x>=off)?sh[threadIdx.x-off]:0u; __syncthreads(); sh[threadIdx.x]+=t; __syncthreads(); }
    if(threadIdx.x<CB) bsS[threadIdx.x]=sh[threadIdx.x]-v2;
    if(threadIdx.x==CB-1) bsS[CB]=sh[threadIdx.x];
}

// ==== scatter with LDS reorder, 512 threads; counts from k_hist ==========
__global__ __launch_bounds__(512) void k_scatter(const int* __restrict__ src, const int* __restrict__ dst,
                          const unsigned* __restrict__ histD, const unsigned* __restrict__ histS,
                          const unsigned* __restrict__ scanD, const unsigned* __restrict__ scanS,
                          const unsigned* __restrict__ bsD, const unsigned* __restrict__ bsS,
                          unsigned* __restrict__ part, unsigned char* __restrict__ spart){
    __shared__ unsigned curD[CB], curS[CB];
    __shared__ unsigned lhD[CB], lhS[CB];
    __shared__ unsigned startD[CB], startS[CB];
    __shared__ unsigned tmp[512];
    __shared__ unsigned partl[CH];
    __shared__ unsigned short keyD[CH];
    __shared__ unsigned short keyS[CH];
    __shared__ unsigned char sl[CH];
    for(int i=threadIdx.x;i<CB;i+=512){
        curD[i]=bsD[i]+scanD[(size_t)blockIdx.x*CB+i];
        curS[i]=bsS[i]+scanS[(size_t)blockIdx.x*CB+i];
        lhD[i]=histD[(size_t)blockIdx.x*CB+i];   // raw per-chunk counts: no atomic pass
        lhS[i]=histS[(size_t)blockIdx.x*CB+i];
    }
    __syncthreads();
    int lo=blockIdx.x*CH, hi=min(lo+CH,NEDGE);
    int n = hi-lo;
    scanCB512(lhD, tmp);
    scanCB512(lhS, tmp);
    for(int i=threadIdx.x;i<CB;i+=512){ startD[i]=lhD[i]; startS[i]=lhS[i]; }
    __syncthreads();
    for(int e=lo+threadIdx.x;e<hi;e+=512){
        int s=src[e], d=dst[e];
        unsigned bd=(unsigned)(d>>8);
        unsigned slot=atomicAdd(&lhD[bd],1u);
        partl[slot]=((unsigned)(d&255)<<18)|(unsigned)s;
        keyD[slot]=(unsigned short)bd;
        unsigned bs=(unsigned)(s>>8);
        unsigned sslot=atomicAdd(&lhS[bs],1u);
        sl[sslot]=(unsigned char)(s&255);
        keyS[sslot]=(unsigned short)bs;
    }
    __syncthreads();
    for(int k=threadIdx.x;k<n;k+=512){
        unsigned b=keyD[k];
        part[curD[b] + (unsigned)k - startD[b]] = partl[k];
    }
    for(int k=threadIdx.x;k<n;k+=512){
        unsigned b=keyS[k];
        spart[curS[b] + (unsigned)k - startS[b]] = sl[k];
    }
}

// ==== fused per-bucket degO + csr (matching CB-grid parallelism) =========
__global__ __launch_bounds__(256) void k_dcsr(const unsigned char* __restrict__ spart, const unsigned* __restrict__ bsS,
                      const unsigned* __restrict__ part, const unsigned* __restrict__ bsD,
                      unsigned* __restrict__ rs, unsigned* __restrict__ degI,
                      unsigned* __restrict__ ec, float* __restrict__ srow, float* __restrict__ rsqI8,
                      float* __restrict__ rsqO, float* __restrict__ sqd){
    __shared__ unsigned cnt[256], cur[256], sh[256];
    __shared__ unsigned stR[256], exR[256];
    __shared__ float rsqOl[256];
    __shared__ unsigned partl[CAP];
    int tid = threadIdx.x;
    int node=(blockIdx.x<<8)+tid;
    // --- phase 1: out-degree ---
    cnt[tid]=0; __syncthreads();
    {
        unsigned slo=bsS[blockIdx.x], shi=bsS[blockIdx.x+1];
        for(unsigned e=slo+tid;e<shi;e+=256) atomicAdd(&cnt[spart[e]],1u);
    }
    __syncthreads();
    {
        float dv = fmaxf((float)cnt[tid],1.f);
        float r = rsqrtf(dv);
        rsqOl[tid]=r;
        if(node<NNODE){
            rsqO[node]=r;                       // for wide k_prep
            sqd[node]=sqrtf(dv)*0.125f;         // (1/rsqO)/8 for scoreloss
        }
    }
    __syncthreads();
    // --- phase 2: csr (padded rows, guard edges) ---
    cnt[tid]=0; __syncthreads();
    unsigned lo=bsD[blockIdx.x], hi=bsD[blockIdx.x+1];
    unsigned n = hi-lo;
    for(unsigned e=lo+tid;e<hi;e+=256) atomicAdd(&cnt[part[e]>>18],1u);
    __syncthreads();
    unsigned c=cnt[tid];
    unsigned r4=(c+3u)&~3u;
    sh[tid]=c; __syncthreads();
    for(int o=1;o<256;o<<=1){ unsigned t2=(tid>=o)?sh[tid-o]:0u; __syncthreads(); sh[tid]+=t2; __syncthreads(); }
    unsigned ex = sh[tid]-c;
    __syncthreads();
    sh[tid]=r4; __syncthreads();
    for(int o=1;o<256;o<<=1){ unsigned t2=(tid>=o)?sh[tid-o]:0u; __syncthreads(); sh[tid]+=t2; __syncthreads(); }
    unsigned ex_r = sh[tid]-r4;
    stR[tid]=ex; exR[tid]=ex_r;
    cur[tid]=(n<=CAP)? ex : ex_r;
    unsigned lo_ec = ((lo+3u)&~3u) + (unsigned)BSLACK*blockIdx.x;
    if(node<NNODE){
        degI[node]=r4; rs[node]=lo_ec+ex_r;
        float rI = rsqrtf(fmaxf((float)c,1.f));   // REAL in-degree for norm
        srow[node]  = rI*rsqOl[tid];   // 8-factors cancel
        rsqI8[node] = rI*0.125f;       // layer-3 epilogue scale
    }
    for(unsigned j=c;j<r4;++j) ec[lo_ec+ex_r+j]=0u;   // guard-fill pads
    __syncthreads();
    if(n <= CAP){
        for(unsigned e=lo+tid;e<hi;e+=256){
            unsigned p=part[e];
            unsigned slot=atomicAdd(&cur[p>>18],1u);
            partl[slot]=p;
        }
        __syncthreads();
        for(unsigned k=tid;k<n;k+=256){
            unsigned p=partl[k];
            unsigned fb=p>>18;
            ec[lo_ec + exR[fb] + (k - stR[fb])] = ((p&0x3FFFFu)+1u)<<7;
        }
    } else {
        for(unsigned e=lo+tid;e<hi;e+=256){
            unsigned p=part[e];
            unsigned pos=lo_ec+atomicAdd(&cur[p>>18],1u);
            ec[pos] = ((p&0x3FFFFu)+1u)<<7;
        }
    }
}

// ==== fp8 prep with 8*rsqO pre-scale + guard rows (wide grid) ============
__global__ __launch_bounds__(256) void k_prep(const float4* __restrict__ ei, const float4* __restrict__ ep,
                      const float* __restrict__ rsqO,
                      unsigned* __restrict__ hE32, unsigned* __restrict__ h1g, unsigned* __restrict__ h2g){
    if(blockIdx.x == PREPB){
        int t = threadIdx.x;
        if(t < 32) hE32[t] = 0u;              // guard row: fp8 zeros
        else if(t < 64) h1g[t-32] = 0u;
        else if(t < 96) h2g[t-64] = 0u;
        return;
    }
    int idx = blockIdx.x*256 + threadIdx.x;
    int n = idx>>5, c = idx&31;
    float sc = 8.f*rsqO[n];                   // stored = 8*rsqO*h  (keeps e4m3 in normal range)
    float4 v;
    if(c<16) v = ei[(size_t)n*16 + c];
    else     v = ep[(size_t)n*16 + (c-16)];
    int d = __builtin_amdgcn_cvt_pk_fp8_f32(v.x*sc, v.y*sc, 0, false);
    d = __builtin_amdgcn_cvt_pk_fp8_f32(v.z*sc, v.w*sc, d, true);
    hE32[32 + (size_t)n*32 + c] = (unsigned)d;   // +32 dwords skips guard row
}

// ==== SpMM: 4 rows/wave joint loop + rotating e-prefetch =================
__device__ __forceinline__ void drain4(const char* __restrict__ hb,
                                       const unsigned* __restrict__ ec,
                                       unsigned s, unsigned c, unsigned &i, unsigned lane2,
                                       v2f &acc){
    for(; i+4<=c; i+=4){
        v4u e = nt4(&ec[s+i]);
        unsigned short u0=*(const unsigned short*)(hb+e.x+lane2);
        unsigned short u1=*(const unsigned short*)(hb+e.y+lane2);
        unsigned short u2=*(const unsigned short*)(hb+e.z+lane2);
        unsigned short u3=*(const unsigned short*)(hb+e.w+lane2);
        acc += fp8x2_to_f32(u0); acc += fp8x2_to_f32(u1);
        acc += fp8x2_to_f32(u2); acc += fp8x2_to_f32(u3);
    }
}

__global__ __launch_bounds__(256) void k_spmm_c(const unsigned short* __restrict__ hinb, unsigned short* __restrict__ houtb,
                                                const unsigned* __restrict__ rs, const unsigned* __restrict__ degI,
                                                const unsigned* __restrict__ ec, const float* __restrict__ srow){
    int wv = (blockIdx.x*256 + threadIdx.x) >> 6;
    int lane = threadIdx.x & 63;
    int r = 4*wv;                         // NNODE % 4 == 0, natural order
    if(r >= NNODE) return;
    unsigned s0=rfl(rs[r  ]), c0=rfl(degI[r  ]);
    unsigned s1=rfl(rs[r+1]), c1=rfl(degI[r+1]);
    unsigned s2=rfl(rs[r+2]), c2=rfl(degI[r+2]);
    unsigned s3=rfl(rs[r+3]), c3=rfl(degI[r+3]);
    const char* hb = (const char*)hinb;
    unsigned lane2 = ((unsigned)lane)*2u;
    v2f a0={0.f,0.f}, a1={0.f,0.f}, a2={0.f,0.f}, a3={0.f,0.f};
    unsigned m = umin2(umin2(c0,c1), umin2(c2,c3));   // multiple of 4
    v4u eA, eB, eC, eD;
    if(m){
        eA=nt4(&ec[s0]); eB=nt4(&ec[s1]); eC=nt4(&ec[s2]); eD=nt4(&ec[s3]);
    }
    for(unsigned i=0; i<m; i+=4){
        unsigned ip = (i+4<m) ? i+4 : 0u;            // clamped: last iter reloads offset 0
        v4u fA=nt4(&ec[s0+ip]), fB=nt4(&ec[s1+ip]), fC=nt4(&ec[s2+ip]), fD=nt4(&ec[s3+ip]);
        unsigned short u00=*(const unsigned short*)(hb+eA.x+lane2);
        unsigned short u01=*(const unsigned short*)(hb+eA.y+lane2);
        unsigned short u02=*(const unsigned short*)(hb+eA.z+lane2);
        unsigned short u03=*(const unsigned short*)(hb+eA.w+lane2);
        unsigned short u10=*(const unsigned short*)(hb+eB.x+lane2);
        unsigned short u11=*(const unsigned short*)(hb+eB.y+lane2);
        unsigned short u12=*(const unsigned short*)(hb+eB.z+lane2);
        unsigned short u13=*(const unsigned short*)(hb+eB.w+lane2);
        unsigned short u20=*(const unsigned short*)(hb+eC.x+lane2);
        unsigned short u21=*(const unsigned short*)(hb+eC.y+lane2);
        unsigned short u22=*(const unsigned short*)(hb+eC.z+lane2);
        unsigned short u23=*(const unsigned short*)(hb+eC.w+lane2);
        unsigned short u30=*(const unsigned short*)(hb+eD.x+lane2);
        unsigned short u31=*(const unsigned short*)(hb+eD.y+lane2);
        unsigned short u32v=*(const unsigned short*)(hb+eD.z+lane2);
        unsigned short u33=*(const unsigned short*)(hb+eD.w+lane2);
        a0 += fp8x2_to_f32(u00); a0 += fp8x2_to_f32(u01); a0 += fp8x2_to_f32(u02); a0 += fp8x2_to_f32(u03);
        a1 += fp8x2_to_f32(u10); a1 += fp8x2_to_f32(u11); a1 += fp8x2_to_f32(u12); a1 += fp8x2_to_f32(u13);
        a2 += fp8x2_to_f32(u20); a2 += fp8x2_to_f32(u21); a2 += fp8x2_to_f32(u22); a2 += fp8x2_to_f32(u23);
        a3 += fp8x2_to_f32(u30); a3 += fp8x2_to_f32(u31); a3 += fp8x2_to_f32(u32v); a3 += fp8x2_to_f32(u33);
        eA=fA; eB=fB; eC=fC; eD=fD;
    }
    unsigned i0=m,i1=m,i2=m,i3=m;
    drain4(hb, ec, s0, c0, i0, lane2, a0);
    drain4(hb, ec, s1, c1, i1, lane2, a1);
    drain4(hb, ec, s2, c2, i2, lane2, a2);
    drain4(hb, ec, s3, c3, i3, lane2, a3);
    float sc0=srow[r], sc1=srow[r+1], sc2=srow[r+2], sc3=srow[r+3];
    houtb[(size_t)(r+1)*64+lane] = f32_to_fp8x2(sc0*a0.x, sc0*a0.y);
    houtb[(size_t)(r+2)*64+lane] = f32_to_fp8x2(sc1*a1.x, sc1*a1.y);
    houtb[(size_t)(r+3)*64+lane] = f32_to_fp8x2(sc2*a2.x, sc2*a2.y);
    houtb[(size_t)(r+4)*64+lane] = f32_to_fp8x2(sc3*a3.x, sc3*a3.y);
}

// ==== fused layer-3 gather + score + loss: one wave per sample ===========
__global__ __launch_bounds__(256) void k_scoreloss(const float2* __restrict__ ei, const float2* __restrict__ ep,
                        const unsigned short* __restrict__ h1C, const unsigned short* __restrict__ h2C,
                        const unsigned* __restrict__ rs, const unsigned* __restrict__ degI,
                        const unsigned* __restrict__ ec, const float* __restrict__ rsqI8,
                        const float* __restrict__ q, const float* __restrict__ bq,
                        const int* __restrict__ user, const int* __restrict__ item_p, const int* __restrict__ item_n,
                        const void* __restrict__ mask, const unsigned* __restrict__ mflag,
                        const float* __restrict__ sqd,
                        float4* __restrict__ partial){
    int t = blockIdx.x*256 + threadIdx.x;
    int b = t >> 6, l = t & 63;
    int wv = threadIdx.x >> 6;
    __shared__ float4 wsum[4];
    int nu = __builtin_amdgcn_readfirstlane(user[b]);
    int np = __builtin_amdgcn_readfirstlane(item_p[b]) + N_USER;
    int nn = __builtin_amdgcn_readfirstlane(item_n[b]) + N_USER;

    // --- in-wave layer-3 gather over h2C for the 3 target rows ---
    unsigned s0 = rfl(rs[nu]), c0 = rfl(degI[nu]);
    unsigned s1 = rfl(rs[np]), c1 = rfl(degI[np]);
    unsigned s2 = rfl(rs[nn]), c2 = rfl(degI[nn]);
    const char* hb = (const char*)h2C;
    unsigned lane2 = ((unsigned)l)*2u;
    v2f g0={0.f,0.f}, g1={0.f,0.f}, g2={0.f,0.f};
    unsigned m = umin2(umin2(c0,c1), c2);
    for(unsigned i=0; i<m; i+=4){
        v4u eA=nt4(&ec[s0+i]), eB=nt4(&ec[s1+i]), eC=nt4(&ec[s2+i]);
        unsigned short u0=*(const unsigned short*)(hb+eA.x+lane2);
        unsigned short u1=*(const unsigned short*)(hb+eA.y+lane2);
        unsigned short u2=*(const unsigned short*)(hb+eA.z+lane2);
        unsigned short u3=*(const unsigned short*)(hb+eA.w+lane2);
        unsigned short u4=*(const unsigned short*)(hb+eB.x+lane2);
        unsigned short u5=*(const unsigned short*)(hb+eB.y+lane2);
        unsigned short u6=*(const unsigned short*)(hb+eB.z+lane2);
        unsigned short u7=*(const unsigned short*)(hb+eB.w+lane2);
        unsigned short u8=*(const unsigned short*)(hb+eC.x+lane2);
        unsigned short u9=*(const unsigned short*)(hb+eC.y+lane2);
        unsigned short ua=*(const unsigned short*)(hb+eC.z+lane2);
        unsigned short ub=*(const unsigned short*)(hb+eC.w+lane2);
        g0 += fp8x2_to_f32(u0); g0 += fp8x2_to_f32(u1); g0 += fp8x2_to_f32(u2); g0 += fp8x2_to_f32(u3);
        g1 += fp8x2_to_f32(u4); g1 += fp8x2_to_f32(u5); g1 += fp8x2_to_f32(u6); g1 += fp8x2_to_f32(u7);
        g2 += fp8x2_to_f32(u8); g2 += fp8x2_to_f32(u9); g2 += fp8x2_to_f32(ua); g2 += fp8x2_to_f32(ub);
    }
    unsigned i0=m, i1=m, i2=m;
    drain4(hb, ec, s0, c0, i0, lane2, g0);
    drain4(hb, ec, s1, c1, i1, lane2, g1);
    drain4(hb, ec, s2, c2, i2, lane2, g2);
    float t0s = rsqI8[nu], t1s = rsqI8[np], t2s = rsqI8[nn];
    float2 h3u = make_float2(g0.x*t0s, g0.y*t0s);
    float2 h3p = make_float2(g1.x*t1s, g1.y*t1s);
    float2 h3n = make_float2(g2.x*t2s, g2.y*t2s);

    // --- score epilogue ---
    float2 e0u, e0p, e0n;
    if(l < 32){
        e0u = ei[(size_t)nu*32 + l]; e0p = ei[(size_t)np*32 + l]; e0n = ei[(size_t)nn*32 + l];
    } else {
        e0u = ep[(size_t)nu*32 + (l-32)]; e0p = ep[(size_t)np*32 + (l-32)]; e0n = ep[(size_t)nn*32 + (l-32)];
    }
    v2f h1u = fp8x2_to_f32(h1C[(size_t)(nu+1)*64 + l]);
    v2f h1p = fp8x2_to_f32(h1C[(size_t)(np+1)*64 + l]);
    v2f h1n = fp8x2_to_f32(h1C[(size_t)(nn+1)*64 + l]);
    v2f h2u = fp8x2_to_f32(h2C[(size_t)(nu+1)*64 + l]);
    v2f h2p = fp8x2_to_f32(h2C[(size_t)(np+1)*64 + l]);
    v2f h2n = fp8x2_to_f32(h2C[(size_t)(nn+1)*64 + l]);

    float squ = sqd[nu], sqp = sqd[np], sqn = sqd[nn];  // sqrt(deg)/8: unscales stored h1+h2

    float fux = e0u.x + squ*(h1u.x + h2u.x) + h3u.x, fuy = e0u.y + squ*(h1u.y + h2u.y) + h3u.y;
    float fpx = e0p.x + sqp*(h1p.x + h2p.x) + h3p.x, fpy = e0p.y + sqp*(h1p.y + h2p.y) + h3p.y;
    float fnx = e0n.x + sqn*(h1n.x + h2n.x) + h3n.x, fny = e0n.y + sqn*(h1n.y + h2n.y) + h3n.y;

    float dp = fux*fpx + fuy*fpy;
    float dn = fux*fnx + fuy*fny;
    for(int off=16; off; off>>=1){ dp += __shfl_down(dp,off,32); dn += __shfl_down(dn,off,32); }
    float pi  = __shfl(dp, 0, 64) * (1.f/16.f);
    float ni  = __shfl(dn, 0, 64) * (1.f/16.f);
    float pp  = __shfl(dp, 32, 64) * (1.f/16.f);
    float npp = __shfl(dn, 32, 64) * (1.f/16.f);
    if(l == 0){
        bool bytes = (*mflag)!=0;
        float mf = bytes ? (((const unsigned char*)mask)[b]?1.f:0.f)
                         : (((const int*)mask)[b]?1.f:0.f);
        float nmf = 1.f-mf;
        float a0 = mf  * logsigf(pi-ni);
        float a1 = mf  * logsigf(npp-pp);
        float a2 = nmf * logsigf(pp-npp);
        int ip=item_p[b], in_=item_n[b];
        float popp = softplusf(q[ip]) + softplusf(bq[ip]);
        float popn = softplusf(q[in_]) + softplusf(bq[in_]);
        float a3 = logsigf(tanhf(popp)*(pi+pp) - tanhf(popn)*(ni+npp));
        wsum[wv] = make_float4(a0,a1,a2,a3);
    }
    __syncthreads();
    if(threadIdx.x == 0){
        float4 s0v=wsum[0], s1v=wsum[1], s2v=wsum[2], s3v=wsum[3];
        partial[blockIdx.x] = make_float4(s0v.x+s1v.x+s2v.x+s3v.x, s0v.y+s1v.y+s2v.y+s3v.y,
                                          s0v.z+s1v.z+s2v.z+s3v.z, s0v.w+s1v.w+s2v.w+s3v.w);
    }
}

__global__ __launch_bounds__(256) void k_lossfin(const float4* __restrict__ partial, float* __restrict__ out){
    __shared__ float4 sh[256];
    float4 s = make_float4(0,0,0,0);
    for(int i=threadIdx.x; i<LBLK; i+=256){
        float4 v = partial[i];
        s.x+=v.x; s.y+=v.y; s.z+=v.z; s.w+=v.w;
    }
    sh[threadIdx.x]=s;
    __syncthreads();
    for(int off=128; off; off>>=1){
        if(threadIdx.x < off){
            float4 a=sh[threadIdx.x], b2=sh[threadIdx.x+off];
            sh[threadIdx.x]=make_float4(a.x+b2.x,a.y+b2.y,a.z+b2.z,a.w+b2.w);
        }
        __syncthreads();
    }
    if(threadIdx.x==0){
        const float invB = 1.f/(float)BSZ;
        float4 t = sh[0];
        float loss_int  = -t.x*invB;
        float loss_pop  = -t.y*invB + t.z*invB;
        float loss_tide = -t.w*invB;
        out[0] = 0.1f*loss_int + 0.1f*loss_pop + 0.2f*loss_tide;
    }
}

extern "C" void kernel_launch(void* const* d_in, const int* in_sizes, int n_in,
                              void* d_out, int out_size, void* d_ws, size_t ws_size,
                              hipStream_t stream){
    const float* emb_int = (const float*)d_in[0];
    const float* emb_pop = (const float*)d_in[1];
    const float* q    = (const float*)d_in[2];
    const float* bq   = (const float*)d_in[3];
    const int* user   = (const int*)d_in[4];
    const int* item_p = (const int*)d_in[5];
    const int* item_n = (const int*)d_in[6];
    const void* mask  = d_in[7];
    const int* esrc   = (const int*)d_in[8];
    const int* edst   = (const int*)d_in[9];

    char* ws = (char*)d_ws;
    size_t o = 0;
    auto take = [&](size_t bytes)->char*{ char* p = ws + o; o = (o + bytes + 255) & ~(size_t)255; return p; };
    unsigned* histD = (unsigned*)take((size_t)NB*CB*4);
    unsigned* histS = (unsigned*)take((size_t)NB*CB*4);
    unsigned* scanD = (unsigned*)take((size_t)NB*CB*4);
    unsigned* scanS = (unsigned*)take((size_t)NB*CB*4);
    unsigned* ctD   = (unsigned*)take((size_t)CB*4);
    unsigned* ctS   = (unsigned*)take((size_t)CB*4);
    unsigned* bsD   = (unsigned*)take((size_t)(CB+1)*4);
    unsigned* bsS   = (unsigned*)take((size_t)(CB+1)*4);
    unsigned* part  = (unsigned*)take((size_t)NEDGE*4);
    unsigned char* spart = (unsigned char*)take((size_t)NEDGE);
    float*    rsqO  = (float*)take((size_t)NNODE*4);
    float*    sqd   = (float*)take((size_t)NNODE*4);
    unsigned* rs    = (unsigned*)take((size_t)NNODE*4);
    unsigned* degI  = (unsigned*)take((size_t)NNODE*4);
    unsigned* ec    = (unsigned*)take((size_t)(NEDGE + BSLACK*CB + 16)*4);  // padded rows
    float*    srow  = (float*)take((size_t)NNODE*4);
    float*    rsqI8 = (float*)take((size_t)NNODE*4);
    unsigned short* hEb  = (unsigned short*)take((size_t)(NNODE+1)*64*2);  // guard row 0
    unsigned short* h1Cb = (unsigned short*)take((size_t)(NNODE+1)*64*2);
    unsigned short* h2Cb = (unsigned short*)take((size_t)(NNODE+1)*64*2);
    float4*   partial = (float4*)take((size_t)LBLK*16);
    unsigned* mflag = (unsigned*)take(256);
    (void)ws_size; (void)in_sizes; (void)n_in; (void)out_size;

    k_hist<<<NB+1,512,0,stream>>>(esrc, edst, histD, histS,
                                  (const unsigned char*)mask, mflag);
    k_colscan<<<dim3(CB,2),512,0,stream>>>(histD, histS, scanD, scanS, ctD, ctS);
    k_bstart<<<1,1024,0,stream>>>(ctD, ctS, bsD, bsS);
    k_scatter<<<NB,512,0,stream>>>(esrc, edst, histD, histS, scanD, scanS,
                                   bsD, bsS, part, spart);
    k_dcsr<<<CB,256,0,stream>>>(spart, bsS, part, bsD,
                                rs, degI, ec, srow, rsqI8, rsqO, sqd);
    k_prep<<<PREPB+1,256,0,stream>>>((const float4*)emb_int, (const float4*)emb_pop, rsqO,
                                     (unsigned*)hEb, (unsigned*)h1Cb, (unsigned*)h2Cb);

    const int spB = ((NNODE/4)*64 + 255)/256;     // one wave per 4 rows
    k_spmm_c<<<spB,256,0,stream>>>(hEb,  h1Cb, rs, degI, ec, srow);  // layer 1
    k_spmm_c<<<spB,256,0,stream>>>(h1Cb, h2Cb, rs, degI, ec, srow);  // layer 2
    k_scoreloss<<<LBLK,256,0,stream>>>((const float2*)emb_int, (const float2*)emb_pop,
                                       h1Cb, h2Cb, rs, degI, ec, rsqI8,
                                       q, bq, user, item_p, item_n,
                                       mask, mflag, sqd, partial);
    k_lossfin<<<1,256,0,stream>>>(partial, (float*)d_out);
}